// Round 4
// baseline (418.470 us; speedup 1.0000x reference)
//
#include <hip/hip_runtime.h>

typedef unsigned short u16;
typedef unsigned int u32;
typedef __bf16 bf16x8 __attribute__((ext_vector_type(8)));
typedef float f32x4 __attribute__((ext_vector_type(4)));
typedef float f32x16 __attribute__((ext_vector_type(16)));

// ---------- helpers ----------
__device__ __forceinline__ u16 f2bf(float f) {
    u32 u = __builtin_bit_cast(u32, f);
    u32 r = u + 0x7FFFu + ((u >> 16) & 1u);   // round-to-nearest-even
    return (u16)(r >> 16);
}
// pack two f32 -> bf16x2 (round-half-up); v0 low, v1 high
__device__ __forceinline__ u32 pack_bf16(float v0, float v1) {
    u32 a = __builtin_bit_cast(u32, v0) + 0x8000u;
    u32 b = __builtin_bit_cast(u32, v1) + 0x8000u;
    return __builtin_amdgcn_perm(b, a, 0x07060302u);  // {b.hi16, a.hi16}
}
// async global->LDS, 16B per lane; dest = l + lane*16B (wave-uniform base)
__device__ __forceinline__ void gload16(const u16* g, u16* l) {
    __builtin_amdgcn_global_load_lds(
        (const __attribute__((address_space(1))) u32*)g,
        (__attribute__((address_space(3))) u32*)l, 16, 0, 0);
}

#define QSCALE 0.18033688011111793f   // (1/8) * log2(e): base-2 softmax domain

// ---------- f32 -> bf16 conversion ----------
__global__ __launch_bounds__(256) void cvt_kernel(const float* __restrict__ in,
                                                  u16* __restrict__ out, int n4) {
    int i = blockIdx.x * 256 + threadIdx.x;
    if (i >= n4) return;
    float4 f = reinterpret_cast<const float4*>(in)[i];
    u32 lo = (u32)f2bf(f.x) | ((u32)f2bf(f.y) << 16);
    u32 hi = (u32)f2bf(f.z) | ((u32)f2bf(f.w) << 16);
    reinterpret_cast<uint2*>(out)[i] = make_uint2(lo, hi);
}

// ---------- GEMM1 fused: qkv = x @ attn_w^T, epilogue does RoPE + scatter + V^T ----------
// 128x128 tile, BK=32, m97-style global_load_lds staging. Each wave's 64-col half
// is exactly one (group, slot): slot<4 -> q (RoPE, scaled), slot=4 -> k (RoPE), 5 -> v (transposed).
__global__ __launch_bounds__(256) void gemm_qkv(const u16* __restrict__ A,
                                                const u16* __restrict__ Bw,
                                                const float* __restrict__ cosb,
                                                const float* __restrict__ sinb,
                                                u16* __restrict__ Qo,
                                                u16* __restrict__ Ko,
                                                u16* __restrict__ Vt) {
    __shared__ __align__(16) u16 As[128 * 32];
    __shared__ __align__(16) u16 Bs[128 * 32];
    const int tid = threadIdx.x;
    const int wave = tid >> 6, lane = tid & 63, quad = lane >> 4, l15 = lane & 15;
    const int wm = wave >> 1, wn = wave & 1;
    const int m0 = blockIdx.x * 128, n0 = blockIdx.y * 128;
    const int K = 2048;
    const int lrow = lane >> 2, lcol = (lane & 3) * 8;
    f32x4 acc[4][4];
#pragma unroll
    for (int a = 0; a < 4; a++)
#pragma unroll
        for (int b = 0; b < 4; b++) acc[a][b] = (f32x4){0.f, 0.f, 0.f, 0.f};
    for (int kk = 0; kk < K; kk += 32) {
        __syncthreads();
#pragma unroll
        for (int c = 0; c < 2; c++) {
            const int rA = wave * 32 + c * 16;
            gload16(A  + (size_t)(m0 + rA + lrow) * K + kk + lcol, &As[rA * 32]);
            gload16(Bw + (size_t)(n0 + rA + lrow) * K + kk + lcol, &Bs[rA * 32]);
        }
        __syncthreads();
        bf16x8 af[4], bfr[4];
#pragma unroll
        for (int t = 0; t < 4; t++) {
            af[t]  = *reinterpret_cast<const bf16x8*>(&As[(wm * 64 + t * 16 + l15) * 32 + quad * 8]);
            bfr[t] = *reinterpret_cast<const bf16x8*>(&Bs[(wn * 64 + t * 16 + l15) * 32 + quad * 8]);
        }
#pragma unroll
        for (int tm = 0; tm < 4; tm++)
#pragma unroll
            for (int tn = 0; tn < 4; tn++)
                acc[tm][tn] = __builtin_amdgcn_mfma_f32_16x16x32_bf16(af[tm], bfr[tn], acc[tm][tn], 0, 0, 0);
    }
    // ---- fused epilogue ----
    const int slot_base = n0 + wn * 64;       // wave-uniform
    const int G = slot_base / 384;
    const int slot = (slot_base % 384) / 64;
    const int bb = m0 >> 11;
    const int tb0 = (m0 & 2047) + wm * 64 + quad * 4;
    if (slot == 5) {
        // V: write transposed Vt[(bb*8+G)*64 + d][t], 4 consecutive t per uint2
        u16* vbase = Vt + ((size_t)(bb * 8 + G) * 64) * 2048;
#pragma unroll
        for (int tm = 0; tm < 4; tm++) {
            const int trow = tb0 + tm * 16;
#pragma unroll
            for (int tn = 0; tn < 4; tn++) {
                const int d = tn * 16 + l15;
                uint2 pk;
                pk.x = pack_bf16(acc[tm][tn][0], acc[tm][tn][1]);
                pk.y = pack_bf16(acc[tm][tn][2], acc[tm][tn][3]);
                *reinterpret_cast<uint2*>(vbase + (size_t)d * 2048 + trow) = pk;
            }
        }
    } else {
        const float sc = (slot < 4) ? QSCALE : 1.0f;
        u16* obase = (slot < 4)
            ? Qo + ((size_t)(bb * 32 + G * 4 + slot) * 2048) * 64
            : Ko + ((size_t)(bb * 8 + G) * 2048) * 64;
#pragma unroll
        for (int tm = 0; tm < 4; tm++) {
#pragma unroll
            for (int i = 0; i < 4; i++) {
                const int t = tb0 + tm * 16 + i;
#pragma unroll
                for (int tn = 0; tn < 2; tn++) {
                    const int dh = tn * 16 + l15;
                    float c = cosb[t * 32 + dh], s = sinb[t * 32 + dh];
                    float x1 = acc[tm][tn][i], x2 = acc[tm][tn + 2][i];
                    obase[(size_t)t * 64 + dh]      = f2bf((x1 * c - x2 * s) * sc);
                    obase[(size_t)t * 64 + dh + 32] = f2bf((x2 * c + x1 * s) * sc);
                }
            }
        }
    }
}

// ---------- GEMM2: out[M,N] f32 = A[M,K] @ B[N,K]^T ----------
__global__ __launch_bounds__(256) void gemm_bt(const u16* __restrict__ A,
                                               const u16* __restrict__ Bw,
                                               float* __restrict__ Cf,
                                               int M, int N, int K) {
    __shared__ __align__(16) u16 As[128 * 32];
    __shared__ __align__(16) u16 Bs[128 * 32];
    const int tid = threadIdx.x;
    const int wave = tid >> 6, lane = tid & 63, quad = lane >> 4, l15 = lane & 15;
    const int wm = wave >> 1, wn = wave & 1;
    const int m0 = blockIdx.x * 128, n0 = blockIdx.y * 128;
    const int lrow = lane >> 2, lcol = (lane & 3) * 8;
    f32x4 acc[4][4];
#pragma unroll
    for (int a = 0; a < 4; a++)
#pragma unroll
        for (int b = 0; b < 4; b++) acc[a][b] = (f32x4){0.f, 0.f, 0.f, 0.f};
    for (int kk = 0; kk < K; kk += 32) {
        __syncthreads();
#pragma unroll
        for (int c = 0; c < 2; c++) {
            const int rA = wave * 32 + c * 16;
            gload16(A  + (size_t)(m0 + rA + lrow) * K + kk + lcol, &As[rA * 32]);
            gload16(Bw + (size_t)(n0 + rA + lrow) * K + kk + lcol, &Bs[rA * 32]);
        }
        __syncthreads();
        bf16x8 af[4], bfr[4];
#pragma unroll
        for (int t = 0; t < 4; t++) {
            af[t]  = *reinterpret_cast<const bf16x8*>(&As[(wm * 64 + t * 16 + l15) * 32 + quad * 8]);
            bfr[t] = *reinterpret_cast<const bf16x8*>(&Bs[(wn * 64 + t * 16 + l15) * 32 + quad * 8]);
        }
#pragma unroll
        for (int tm = 0; tm < 4; tm++)
#pragma unroll
            for (int tn = 0; tn < 4; tn++)
                acc[tm][tn] = __builtin_amdgcn_mfma_f32_16x16x32_bf16(af[tm], bfr[tn], acc[tm][tn], 0, 0, 0);
    }
#pragma unroll
    for (int tm = 0; tm < 4; tm++) {
        const int r0 = m0 + wm * 64 + tm * 16 + quad * 4;
#pragma unroll
        for (int tn = 0; tn < 4; tn++) {
            const int c = n0 + wn * 64 + tn * 16 + l15;
#pragma unroll
            for (int i = 0; i < 4; i++) Cf[(size_t)(r0 + i) * N + c] = acc[tm][tn][i];
        }
    }
}

// ---------- flash attention v3: BQ=128, BK=64, 32x32x16, fixed-max softmax, ----------
// shfl-exchanged P (no LDS round-trip), double-buffered K/V (1 barrier/iter).
__global__ __launch_bounds__(256, 4) void attn(const u16* __restrict__ Q,
                                               const u16* __restrict__ Kg,
                                               const u16* __restrict__ Vt,
                                               u16* __restrict__ O) {
    constexpr int LDK = 72;
    constexpr int TS = 64 * LDK;              // one K or V tile (u16 elems)
    __shared__ __align__(16) u16 lds[4 * TS]; // [K0 V0 K1 V1], 36864 B
    const int tid = threadIdx.x, w = tid >> 6, lane = tid & 63;
    const int half = lane >> 5, l31 = lane & 31;
    const int q0 = blockIdx.x * 128;
    const int h = blockIdx.y, b = blockIdx.z, g = h >> 2;
    const u16* qb = Q + (((size_t)(b * 32 + h)) * 2048 + q0) * 64;
    const u16* kb = Kg + ((size_t)(b * 8 + g)) * 2048 * 64;
    const u16* vb = Vt + ((size_t)(b * 8 + g)) * 64 * 2048;

    // stage Q (128 x 64) across lds[0..128*LDK), read per-wave B-fragments
    {
        const int r = tid >> 3, c = tid & 7;
#pragma unroll
        for (int p = 0; p < 4; p++) {
            uint4 d = *reinterpret_cast<const uint4*>(qb + (size_t)(r + p * 32) * 64 + c * 8);
            *reinterpret_cast<uint4*>(&lds[(r + p * 32) * LDK + c * 8]) = d;
        }
    }
    __syncthreads();
    bf16x8 qf[4];
#pragma unroll
    for (int ks = 0; ks < 4; ks++)
        qf[ks] = *reinterpret_cast<const bf16x8*>(&lds[(w * 32 + l31) * LDK + ks * 16 + half * 8]);
    __syncthreads();

    // stage tile 0 into buffer 0
    const int rk = tid >> 3, ck = tid & 7;
#pragma unroll
    for (int p = 0; p < 2; p++) {
        const int r = rk + p * 32;
        uint4 dk = *reinterpret_cast<const uint4*>(kb + (size_t)r * 64 + ck * 8);
        uint4 dv = *reinterpret_cast<const uint4*>(vb + (size_t)r * 2048 + ck * 8);
        *reinterpret_cast<uint4*>(&lds[0 * TS + r * LDK + ck * 8]) = dk;
        *reinterpret_cast<uint4*>(&lds[1 * TS + r * LDK + ck * 8]) = dv;
    }
    __syncthreads();

    f32x16 Oa[2];
#pragma unroll
    for (int t = 0; t < 2; t++)
#pragma unroll
        for (int i = 0; i < 16; i++) Oa[t][i] = 0.f;
    float lsum = 0.f;

    for (int kk = 0; kk < 2048; kk += 64) {
        const int cur = (kk >> 6) & 1;
        const u16* Kc = lds + 2 * cur * TS;
        const u16* Vc = Kc + TS;
        // prefetch next tile into registers (hides global latency behind compute)
        uint4 pk[2], pv[2];
        const bool have = (kk + 64) < 2048;
        if (have) {
#pragma unroll
            for (int p = 0; p < 2; p++) {
                const int r = rk + p * 32;
                pk[p] = *reinterpret_cast<const uint4*>(kb + (size_t)(kk + 64 + r) * 64 + ck * 8);
                pv[p] = *reinterpret_cast<const uint4*>(vb + (size_t)r * 2048 + kk + 64 + ck * 8);
            }
        }
        // S^T[key][q]
        f32x16 S[2];
#pragma unroll
        for (int kt = 0; kt < 2; kt++) {
#pragma unroll
            for (int i = 0; i < 16; i++) S[kt][i] = 0.f;
#pragma unroll
            for (int ks = 0; ks < 4; ks++) {
                bf16x8 kf = *reinterpret_cast<const bf16x8*>(
                    &Kc[(kt * 32 + l31) * LDK + ks * 16 + half * 8]);
                S[kt] = __builtin_amdgcn_mfma_f32_32x32x16_bf16(kf, qf[ks], S[kt], 0, 0, 0);
            }
        }
        // fixed-max base-2 softmax: p = exp2(s) directly (|s| <~ 9, no overflow)
        float ps = 0.f;
        u32 P2[2][4][2];
#pragma unroll
        for (int kt = 0; kt < 2; kt++)
#pragma unroll
            for (int gr = 0; gr < 4; gr++) {
                float p0 = __builtin_amdgcn_exp2f(S[kt][gr * 4 + 0]);
                float p1 = __builtin_amdgcn_exp2f(S[kt][gr * 4 + 1]);
                float p2 = __builtin_amdgcn_exp2f(S[kt][gr * 4 + 2]);
                float p3 = __builtin_amdgcn_exp2f(S[kt][gr * 4 + 3]);
                ps += (p0 + p1) + (p2 + p3);
                P2[kt][gr][0] = pack_bf16(p0, p1);
                P2[kt][gr][1] = pack_bf16(p2, p3);
            }
        lsum += ps;
        // cross-half exchange: partner's packed pair gr = 2s + 1 - half
        u32 oth[2][2][2];
#pragma unroll
        for (int kt = 0; kt < 2; kt++)
#pragma unroll
            for (int s = 0; s < 2; s++)
#pragma unroll
                for (int j = 0; j < 2; j++)
                    oth[kt][s][j] = __shfl_xor(P2[kt][2 * s + 1 - half][j], 32);
        // O^T += V^T-frag x P-frag
#pragma unroll
        for (int ks2 = 0; ks2 < 4; ks2++) {
            const int kt = ks2 >> 1, s = ks2 & 1;
            uint4 pu;
            pu.x = half ? oth[kt][s][0] : P2[kt][2 * s][0];
            pu.y = half ? oth[kt][s][1] : P2[kt][2 * s][1];
            pu.z = half ? P2[kt][2 * s + 1][0] : oth[kt][s][0];
            pu.w = half ? P2[kt][2 * s + 1][1] : oth[kt][s][1];
            bf16x8 pf = __builtin_bit_cast(bf16x8, pu);
#pragma unroll
            for (int dt = 0; dt < 2; dt++) {
                bf16x8 vf = *reinterpret_cast<const bf16x8*>(
                    &Vc[(dt * 32 + l31) * LDK + ks2 * 16 + half * 8]);
                Oa[dt] = __builtin_amdgcn_mfma_f32_32x32x16_bf16(vf, pf, Oa[dt], 0, 0, 0);
            }
        }
        // write prefetched tile into the other buffer, single barrier
        if (have) {
            u16* Kn = lds + 2 * (cur ^ 1) * TS;
            u16* Vn = Kn + TS;
#pragma unroll
            for (int p = 0; p < 2; p++) {
                const int r = rk + p * 32;
                *reinterpret_cast<uint4*>(&Kn[r * LDK + ck * 8]) = pk[p];
                *reinterpret_cast<uint4*>(&Vn[r * LDK + ck * 8]) = pv[p];
            }
        }
        __syncthreads();
    }
    float lt = lsum + __shfl_xor(lsum, 32);
    float linv = 1.f / lt;
    const int t = q0 + w * 32 + l31;
    u16* orow = O + ((size_t)(b * 2048 + t)) * 2048 + h * 64;
#pragma unroll
    for (int dt = 0; dt < 2; dt++)
#pragma unroll
        for (int gr = 0; gr < 4; gr++) {
            uint2 pk;
            pk.x = pack_bf16(Oa[dt][gr * 4 + 0] * linv, Oa[dt][gr * 4 + 1] * linv);
            pk.y = pack_bf16(Oa[dt][gr * 4 + 2] * linv, Oa[dt][gr * 4 + 3] * linv);
            *reinterpret_cast<uint2*>(orow + dt * 32 + 8 * gr + 4 * half) = pk;
        }
}

// ---------- launch ----------
extern "C" void kernel_launch(void* const* d_in, const int* in_sizes, int n_in,
                              void* d_out, int out_size, void* d_ws, size_t ws_size,
                              hipStream_t stream) {
    const float* x      = (const float*)d_in[0];
    const float* cosb   = (const float*)d_in[1];
    const float* sinb   = (const float*)d_in[2];
    const float* attn_w = (const float*)d_in[3];
    const float* proj_w = (const float*)d_in[4];
    float* out = (float*)d_out;

    u16* xb  = (u16*)d_ws;                       // 4096*2048
    u16* w1b = xb  + (size_t)4096 * 2048;        // 3072*2048
    u16* w2b = w1b + (size_t)3072 * 2048;        // 2048*2048
    u16* qo  = w2b + (size_t)2048 * 2048;        // 2*32*2048*64
    u16* ko  = qo  + (size_t)2 * 32 * 2048 * 64; // 2*8*2048*64
    u16* vt  = ko  + (size_t)2 * 8 * 2048 * 64;  // 2*8*64*2048 (transposed)
    u16* ao  = xb;   // attention output reuses x buffer (x consumed by gemm_qkv)

    cvt_kernel<<<8192, 256, 0, stream>>>(x, xb, 4096 * 2048 / 4);
    cvt_kernel<<<6144, 256, 0, stream>>>(attn_w, w1b, 3072 * 2048 / 4);
    cvt_kernel<<<4096, 256, 0, stream>>>(proj_w, w2b, 2048 * 2048 / 4);
    gemm_qkv<<<dim3(32, 24), 256, 0, stream>>>(xb, w1b, cosb, sinb, qo, ko, vt);
    attn<<<dim3(16, 32, 2), 256, 0, stream>>>(qo, ko, vt, ao);
    gemm_bt<<<dim3(32, 16), 256, 0, stream>>>(ao, w2b, out, 4096, 2048, 2048);
}

// Round 6
// 378.570 us; speedup vs baseline: 1.1054x; 1.1054x over previous
//
#include <hip/hip_runtime.h>

typedef unsigned short u16;
typedef unsigned int u32;
typedef __bf16 bf16x8 __attribute__((ext_vector_type(8)));
typedef float f32x4 __attribute__((ext_vector_type(4)));
typedef float f32x16 __attribute__((ext_vector_type(16)));

// ---------- helpers ----------
__device__ __forceinline__ u16 f2bf(float f) {
    u32 u = __builtin_bit_cast(u32, f);
    u32 r = u + 0x7FFFu + ((u >> 16) & 1u);   // round-to-nearest-even
    return (u16)(r >> 16);
}
// pack two f32 -> bf16x2 (round-half-up); v0 low, v1 high
__device__ __forceinline__ u32 pack_bf16(float v0, float v1) {
    u32 a = __builtin_bit_cast(u32, v0) + 0x8000u;
    u32 b = __builtin_bit_cast(u32, v1) + 0x8000u;
    return __builtin_amdgcn_perm(b, a, 0x07060302u);  // {b.hi16, a.hi16}
}
// async global->LDS, 16B per lane; dest = l + lane*16B (wave-uniform base)
__device__ __forceinline__ void gload16(const u16* g, u16* l) {
    __builtin_amdgcn_global_load_lds(
        (const __attribute__((address_space(1))) u32*)g,
        (__attribute__((address_space(3))) u32*)l, 16, 0, 0);
}

#define QSCALE 0.18033688011111793f   // (1/8) * log2(e): base-2 softmax domain

// ---------- f32 -> bf16 conversion ----------
__global__ __launch_bounds__(256) void cvt_kernel(const float* __restrict__ in,
                                                  u16* __restrict__ out, int n4) {
    int i = blockIdx.x * 256 + threadIdx.x;
    if (i >= n4) return;
    float4 f = reinterpret_cast<const float4*>(in)[i];
    u32 lo = (u32)f2bf(f.x) | ((u32)f2bf(f.y) << 16);
    u32 hi = (u32)f2bf(f.z) | ((u32)f2bf(f.w) << 16);
    reinterpret_cast<uint2*>(out)[i] = make_uint2(lo, hi);
}

// ---------- GEMM1 fused: qkv = x @ attn_w^T, epilogue does RoPE + scatter + V^T ----------
__global__ __launch_bounds__(256) void gemm_qkv(const u16* __restrict__ A,
                                                const u16* __restrict__ Bw,
                                                const float* __restrict__ cosb,
                                                const float* __restrict__ sinb,
                                                u16* __restrict__ Qo,
                                                u16* __restrict__ Ko,
                                                u16* __restrict__ Vt) {
    __shared__ __align__(16) u16 As[128 * 32];
    __shared__ __align__(16) u16 Bs[128 * 32];
    const int tid = threadIdx.x;
    const int wave = tid >> 6, lane = tid & 63, quad = lane >> 4, l15 = lane & 15;
    const int wm = wave >> 1, wn = wave & 1;
    const int m0 = blockIdx.x * 128, n0 = blockIdx.y * 128;
    const int K = 2048;
    const int lrow = lane >> 2, lcol = (lane & 3) * 8;
    f32x4 acc[4][4];
#pragma unroll
    for (int a = 0; a < 4; a++)
#pragma unroll
        for (int b = 0; b < 4; b++) acc[a][b] = (f32x4){0.f, 0.f, 0.f, 0.f};
    for (int kk = 0; kk < K; kk += 32) {
        __syncthreads();
#pragma unroll
        for (int c = 0; c < 2; c++) {
            const int rA = wave * 32 + c * 16;
            gload16(A  + (size_t)(m0 + rA + lrow) * K + kk + lcol, &As[rA * 32]);
            gload16(Bw + (size_t)(n0 + rA + lrow) * K + kk + lcol, &Bs[rA * 32]);
        }
        __syncthreads();
        bf16x8 af[4], bfr[4];
#pragma unroll
        for (int t = 0; t < 4; t++) {
            af[t]  = *reinterpret_cast<const bf16x8*>(&As[(wm * 64 + t * 16 + l15) * 32 + quad * 8]);
            bfr[t] = *reinterpret_cast<const bf16x8*>(&Bs[(wn * 64 + t * 16 + l15) * 32 + quad * 8]);
        }
#pragma unroll
        for (int tm = 0; tm < 4; tm++)
#pragma unroll
            for (int tn = 0; tn < 4; tn++)
                acc[tm][tn] = __builtin_amdgcn_mfma_f32_16x16x32_bf16(af[tm], bfr[tn], acc[tm][tn], 0, 0, 0);
    }
    // ---- fused epilogue ----
    const int slot_base = n0 + wn * 64;       // wave-uniform
    const int G = slot_base / 384;
    const int slot = (slot_base % 384) / 64;
    const int bb = m0 >> 11;
    const int tb0 = (m0 & 2047) + wm * 64 + quad * 4;
    if (slot == 5) {
        u16* vbase = Vt + ((size_t)(bb * 8 + G) * 64) * 2048;
#pragma unroll
        for (int tm = 0; tm < 4; tm++) {
            const int trow = tb0 + tm * 16;
#pragma unroll
            for (int tn = 0; tn < 4; tn++) {
                const int d = tn * 16 + l15;
                uint2 pk;
                pk.x = pack_bf16(acc[tm][tn][0], acc[tm][tn][1]);
                pk.y = pack_bf16(acc[tm][tn][2], acc[tm][tn][3]);
                *reinterpret_cast<uint2*>(vbase + (size_t)d * 2048 + trow) = pk;
            }
        }
    } else {
        const float sc = (slot < 4) ? QSCALE : 1.0f;
        u16* obase = (slot < 4)
            ? Qo + ((size_t)(bb * 32 + G * 4 + slot) * 2048) * 64
            : Ko + ((size_t)(bb * 8 + G) * 2048) * 64;
#pragma unroll
        for (int tm = 0; tm < 4; tm++) {
#pragma unroll
            for (int i = 0; i < 4; i++) {
                const int t = tb0 + tm * 16 + i;
#pragma unroll
                for (int tn = 0; tn < 2; tn++) {
                    const int dh = tn * 16 + l15;
                    float c = cosb[t * 32 + dh], s = sinb[t * 32 + dh];
                    float x1 = acc[tm][tn][i], x2 = acc[tm][tn + 2][i];
                    obase[(size_t)t * 64 + dh]      = f2bf((x1 * c - x2 * s) * sc);
                    obase[(size_t)t * 64 + dh + 32] = f2bf((x2 * c + x1 * s) * sc);
                }
            }
        }
    }
}

// ---------- GEMM2: out[M,N] f32 = A[M,K] @ B[N,K]^T ----------
__global__ __launch_bounds__(256) void gemm_bt(const u16* __restrict__ A,
                                               const u16* __restrict__ Bw,
                                               float* __restrict__ Cf,
                                               int M, int N, int K) {
    __shared__ __align__(16) u16 As[128 * 32];
    __shared__ __align__(16) u16 Bs[128 * 32];
    const int tid = threadIdx.x;
    const int wave = tid >> 6, lane = tid & 63, quad = lane >> 4, l15 = lane & 15;
    const int wm = wave >> 1, wn = wave & 1;
    const int m0 = blockIdx.x * 128, n0 = blockIdx.y * 128;
    const int lrow = lane >> 2, lcol = (lane & 3) * 8;
    f32x4 acc[4][4];
#pragma unroll
    for (int a = 0; a < 4; a++)
#pragma unroll
        for (int b = 0; b < 4; b++) acc[a][b] = (f32x4){0.f, 0.f, 0.f, 0.f};
    for (int kk = 0; kk < K; kk += 32) {
        __syncthreads();
#pragma unroll
        for (int c = 0; c < 2; c++) {
            const int rA = wave * 32 + c * 16;
            gload16(A  + (size_t)(m0 + rA + lrow) * K + kk + lcol, &As[rA * 32]);
            gload16(Bw + (size_t)(n0 + rA + lrow) * K + kk + lcol, &Bs[rA * 32]);
        }
        __syncthreads();
        bf16x8 af[4], bfr[4];
#pragma unroll
        for (int t = 0; t < 4; t++) {
            af[t]  = *reinterpret_cast<const bf16x8*>(&As[(wm * 64 + t * 16 + l15) * 32 + quad * 8]);
            bfr[t] = *reinterpret_cast<const bf16x8*>(&Bs[(wn * 64 + t * 16 + l15) * 32 + quad * 8]);
        }
#pragma unroll
        for (int tm = 0; tm < 4; tm++)
#pragma unroll
            for (int tn = 0; tn < 4; tn++)
                acc[tm][tn] = __builtin_amdgcn_mfma_f32_16x16x32_bf16(af[tm], bfr[tn], acc[tm][tn], 0, 0, 0);
    }
#pragma unroll
    for (int tm = 0; tm < 4; tm++) {
        const int r0 = m0 + wm * 64 + tm * 16 + quad * 4;
#pragma unroll
        for (int tn = 0; tn < 4; tn++) {
            const int c = n0 + wn * 64 + tn * 16 + l15;
#pragma unroll
            for (int i = 0; i < 4; i++) Cf[(size_t)(r0 + i) * N + c] = acc[tm][tn][i];
        }
    }
}

// ---------- flash attention v5: v3's proven skeleton (stores after PV, 1 barrier),
// with prefetch loads issued RIGHT BEFORE their stores (near-zero register live
// range -> no scratch spill). Fixed-max base-2 softmax + shfl-exchanged P.
__global__ __launch_bounds__(256, 4) void attn(const u16* __restrict__ Q,
                                               const u16* __restrict__ Kg,
                                               const u16* __restrict__ Vt,
                                               u16* __restrict__ O) {
    constexpr int LDK = 72;
    constexpr int TS = 64 * LDK;              // one K or V tile (u16 elems)
    __shared__ __align__(16) u16 lds[4 * TS]; // [K0 V0 K1 V1], 36864 B
    const int tid = threadIdx.x, w = tid >> 6, lane = tid & 63;
    const int half = lane >> 5, l31 = lane & 31;
    const int q0 = blockIdx.x * 128;
    const int h = blockIdx.y, b = blockIdx.z, g = h >> 2;
    const u16* qb = Q + (((size_t)(b * 32 + h)) * 2048 + q0) * 64;
    const u16* kb = Kg + ((size_t)(b * 8 + g)) * 2048 * 64;
    const u16* vb = Vt + ((size_t)(b * 8 + g)) * 64 * 2048;

    // stage Q (128 x 64), read per-wave B-fragments
    {
        const int r = tid >> 3, c = tid & 7;
#pragma unroll
        for (int p = 0; p < 4; p++) {
            uint4 d = *reinterpret_cast<const uint4*>(qb + (size_t)(r + p * 32) * 64 + c * 8);
            *reinterpret_cast<uint4*>(&lds[(r + p * 32) * LDK + c * 8]) = d;
        }
    }
    __syncthreads();
    bf16x8 qf[4];
#pragma unroll
    for (int ks = 0; ks < 4; ks++)
        qf[ks] = *reinterpret_cast<const bf16x8*>(&lds[(w * 32 + l31) * LDK + ks * 16 + half * 8]);
    __syncthreads();

    // stage tile 0 into buffer 0
    const int rk = tid >> 3, ck = tid & 7;
#pragma unroll
    for (int p = 0; p < 2; p++) {
        const int r = rk + p * 32;
        uint4 dk = *reinterpret_cast<const uint4*>(kb + (size_t)r * 64 + ck * 8);
        uint4 dv = *reinterpret_cast<const uint4*>(vb + (size_t)r * 2048 + ck * 8);
        *reinterpret_cast<uint4*>(&lds[0 * TS + r * LDK + ck * 8]) = dk;
        *reinterpret_cast<uint4*>(&lds[1 * TS + r * LDK + ck * 8]) = dv;
    }
    __syncthreads();

    f32x16 Oa[2];
#pragma unroll
    for (int t = 0; t < 2; t++)
#pragma unroll
        for (int i = 0; i < 16; i++) Oa[t][i] = 0.f;
    float lsum = 0.f;

    for (int kk = 0; kk < 2048; kk += 64) {
        const int cur = (kk >> 6) & 1;
        const u16* Kc = lds + 2 * cur * TS;
        const u16* Vc = Kc + TS;
        const bool have = (kk + 64) < 2048;
        // S^T[key][q]
        f32x16 S[2];
#pragma unroll
        for (int kt = 0; kt < 2; kt++) {
#pragma unroll
            for (int i = 0; i < 16; i++) S[kt][i] = 0.f;
#pragma unroll
            for (int ks = 0; ks < 4; ks++) {
                bf16x8 kf = *reinterpret_cast<const bf16x8*>(
                    &Kc[(kt * 32 + l31) * LDK + ks * 16 + half * 8]);
                S[kt] = __builtin_amdgcn_mfma_f32_32x32x16_bf16(kf, qf[ks], S[kt], 0, 0, 0);
            }
        }
        // fixed-max base-2 softmax: p = exp2(s) directly (|s| <~ 13, no overflow)
        float ps = 0.f;
        u32 P2[2][4][2];
#pragma unroll
        for (int kt = 0; kt < 2; kt++)
#pragma unroll
            for (int gr = 0; gr < 4; gr++) {
                float p0 = __builtin_amdgcn_exp2f(S[kt][gr * 4 + 0]);
                float p1 = __builtin_amdgcn_exp2f(S[kt][gr * 4 + 1]);
                float p2 = __builtin_amdgcn_exp2f(S[kt][gr * 4 + 2]);
                float p3 = __builtin_amdgcn_exp2f(S[kt][gr * 4 + 3]);
                ps += (p0 + p1) + (p2 + p3);
                P2[kt][gr][0] = pack_bf16(p0, p1);
                P2[kt][gr][1] = pack_bf16(p2, p3);
            }
        lsum += ps;
        // cross-half exchange: partner's packed pair gr = 2s + 1 - half
        u32 oth[2][2][2];
#pragma unroll
        for (int kt = 0; kt < 2; kt++)
#pragma unroll
            for (int s = 0; s < 2; s++)
#pragma unroll
                for (int j = 0; j < 2; j++)
                    oth[kt][s][j] = __shfl_xor(P2[kt][2 * s + 1 - half][j], 32);
        // O^T += V^T-frag x P-frag
#pragma unroll
        for (int ks2 = 0; ks2 < 4; ks2++) {
            const int kt = ks2 >> 1, s = ks2 & 1;
            uint4 pu;
            pu.x = half ? oth[kt][s][0] : P2[kt][2 * s][0];
            pu.y = half ? oth[kt][s][1] : P2[kt][2 * s][1];
            pu.z = half ? P2[kt][2 * s + 1][0] : oth[kt][s][0];
            pu.w = half ? P2[kt][2 * s + 1][1] : oth[kt][s][1];
            bf16x8 pf = __builtin_bit_cast(bf16x8, pu);
#pragma unroll
            for (int dt = 0; dt < 2; dt++) {
                bf16x8 vf = *reinterpret_cast<const bf16x8*>(
                    &Vc[(dt * 32 + l31) * LDK + ks2 * 16 + half * 8]);
                Oa[dt] = __builtin_amdgcn_mfma_f32_32x32x16_bf16(vf, pf, Oa[dt], 0, 0, 0);
            }
        }
        // load + immediately store next tile into the other buffer (v3-proven
        // placement; registers live only across this short block -> no spill)
        if (have) {
            u16* Kn = lds + 2 * (cur ^ 1) * TS;
            u16* Vn = Kn + TS;
            uint4 pk0 = *reinterpret_cast<const uint4*>(kb + (size_t)(kk + 64 + rk) * 64 + ck * 8);
            uint4 pk1 = *reinterpret_cast<const uint4*>(kb + (size_t)(kk + 96 + rk) * 64 + ck * 8);
            uint4 pv0 = *reinterpret_cast<const uint4*>(vb + (size_t)rk * 2048 + kk + 64 + ck * 8);
            uint4 pv1 = *reinterpret_cast<const uint4*>(vb + (size_t)(rk + 32) * 2048 + kk + 64 + ck * 8);
            *reinterpret_cast<uint4*>(&Kn[rk * LDK + ck * 8]) = pk0;
            *reinterpret_cast<uint4*>(&Kn[(rk + 32) * LDK + ck * 8]) = pk1;
            *reinterpret_cast<uint4*>(&Vn[rk * LDK + ck * 8]) = pv0;
            *reinterpret_cast<uint4*>(&Vn[(rk + 32) * LDK + ck * 8]) = pv1;
        }
        __syncthreads();
    }
    float lt = lsum + __shfl_xor(lsum, 32);
    float linv = 1.f / lt;
    const int t = q0 + w * 32 + l31;
    u16* orow = O + ((size_t)(b * 2048 + t)) * 2048 + h * 64;
#pragma unroll
    for (int dt = 0; dt < 2; dt++)
#pragma unroll
        for (int gr = 0; gr < 4; gr++) {
            uint2 pk;
            pk.x = pack_bf16(Oa[dt][gr * 4 + 0] * linv, Oa[dt][gr * 4 + 1] * linv);
            pk.y = pack_bf16(Oa[dt][gr * 4 + 2] * linv, Oa[dt][gr * 4 + 3] * linv);
            *reinterpret_cast<uint2*>(orow + dt * 32 + 8 * gr + 4 * half) = pk;
        }
}

// ---------- launch ----------
extern "C" void kernel_launch(void* const* d_in, const int* in_sizes, int n_in,
                              void* d_out, int out_size, void* d_ws, size_t ws_size,
                              hipStream_t stream) {
    const float* x      = (const float*)d_in[0];
    const float* cosb   = (const float*)d_in[1];
    const float* sinb   = (const float*)d_in[2];
    const float* attn_w = (const float*)d_in[3];
    const float* proj_w = (const float*)d_in[4];
    float* out = (float*)d_out;

    u16* xb  = (u16*)d_ws;                       // 4096*2048
    u16* w1b = xb  + (size_t)4096 * 2048;        // 3072*2048
    u16* w2b = w1b + (size_t)3072 * 2048;        // 2048*2048
    u16* qo  = w2b + (size_t)2048 * 2048;        // 2*32*2048*64
    u16* ko  = qo  + (size_t)2 * 32 * 2048 * 64; // 2*8*2048*64
    u16* vt  = ko  + (size_t)2 * 8 * 2048 * 64;  // 2*8*64*2048 (transposed)
    u16* ao  = xb;   // attention output reuses x buffer (x consumed by gemm_qkv)

    cvt_kernel<<<8192, 256, 0, stream>>>(x, xb, 4096 * 2048 / 4);
    cvt_kernel<<<6144, 256, 0, stream>>>(attn_w, w1b, 3072 * 2048 / 4);
    cvt_kernel<<<4096, 256, 0, stream>>>(proj_w, w2b, 2048 * 2048 / 4);
    gemm_qkv<<<dim3(32, 24), 256, 0, stream>>>(xb, w1b, cosb, sinb, qo, ko, vt);
    attn<<<dim3(16, 32, 2), 256, 0, stream>>>(qo, ko, vt, ao);
    gemm_bt<<<dim3(32, 16), 256, 0, stream>>>(ao, w2b, out, 4096, 2048, 2048);
}

// Round 7
// 340.788 us; speedup vs baseline: 1.2279x; 1.1109x over previous
//
#include <hip/hip_runtime.h>

typedef unsigned short u16;
typedef unsigned int u32;
typedef __bf16 bf16x8 __attribute__((ext_vector_type(8)));
typedef float f32x4 __attribute__((ext_vector_type(4)));
typedef float f32x16 __attribute__((ext_vector_type(16)));

// ---------- helpers ----------
__device__ __forceinline__ u16 f2bf(float f) {
    u32 u = __builtin_bit_cast(u32, f);
    u32 r = u + 0x7FFFu + ((u >> 16) & 1u);   // round-to-nearest-even
    return (u16)(r >> 16);
}
// pack two f32 -> bf16x2 (round-half-up); v0 low, v1 high
__device__ __forceinline__ u32 pack_bf16(float v0, float v1) {
    u32 a = __builtin_bit_cast(u32, v0) + 0x8000u;
    u32 b = __builtin_bit_cast(u32, v1) + 0x8000u;
    return __builtin_amdgcn_perm(b, a, 0x07060302u);  // {b.hi16, a.hi16}
}
// async global->LDS, 16B per lane; LDS dest = l + lane*16B (wave-uniform base);
// global address is per-lane (may be strided)
__device__ __forceinline__ void gload16(const u16* g, u16* l) {
    __builtin_amdgcn_global_load_lds(
        (const __attribute__((address_space(1))) u32*)g,
        (__attribute__((address_space(3))) u32*)l, 16, 0, 0);
}

#define QSCALE 0.18033688011111793f   // (1/8) * log2(e): base-2 softmax domain

// ---------- f32 -> bf16 conversion ----------
__global__ __launch_bounds__(256) void cvt_kernel(const float* __restrict__ in,
                                                  u16* __restrict__ out, int n4) {
    int i = blockIdx.x * 256 + threadIdx.x;
    if (i >= n4) return;
    float4 f = reinterpret_cast<const float4*>(in)[i];
    u32 lo = (u32)f2bf(f.x) | ((u32)f2bf(f.y) << 16);
    u32 hi = (u32)f2bf(f.z) | ((u32)f2bf(f.w) << 16);
    reinterpret_cast<uint2*>(out)[i] = make_uint2(lo, hi);
}

// ---------- GEMM1 fused: qkv = x @ attn_w^T, BK=64 (two BK=32 panels),
// epilogue does RoPE + scatter + V^T ----------
__global__ __launch_bounds__(256) void gemm_qkv(const u16* __restrict__ A,
                                                const u16* __restrict__ Bw,
                                                const float* __restrict__ cosb,
                                                const float* __restrict__ sinb,
                                                u16* __restrict__ Qo,
                                                u16* __restrict__ Ko,
                                                u16* __restrict__ Vt) {
    __shared__ __align__(16) u16 As[2 * 128 * 32];   // panel p at p*4096
    __shared__ __align__(16) u16 Bs[2 * 128 * 32];
    const int tid = threadIdx.x;
    const int wave = tid >> 6, lane = tid & 63, quad = lane >> 4, l15 = lane & 15;
    const int wm = wave >> 1, wn = wave & 1;
    const int m0 = blockIdx.x * 128, n0 = blockIdx.y * 128;
    const int K = 2048;
    const int lrow = lane >> 2, lcol = (lane & 3) * 8;
    f32x4 acc[4][4];
#pragma unroll
    for (int a = 0; a < 4; a++)
#pragma unroll
        for (int b = 0; b < 4; b++) acc[a][b] = (f32x4){0.f, 0.f, 0.f, 0.f};
    for (int kk = 0; kk < K; kk += 64) {
        __syncthreads();
#pragma unroll
        for (int p = 0; p < 2; p++)
#pragma unroll
            for (int c = 0; c < 2; c++) {
                const int rA = wave * 32 + c * 16;
                gload16(A  + (size_t)(m0 + rA + lrow) * K + kk + p * 32 + lcol,
                        &As[p * 4096 + rA * 32]);
                gload16(Bw + (size_t)(n0 + rA + lrow) * K + kk + p * 32 + lcol,
                        &Bs[p * 4096 + rA * 32]);
            }
        __syncthreads();
#pragma unroll
        for (int p = 0; p < 2; p++) {
            bf16x8 af[4], bfr[4];
#pragma unroll
            for (int t = 0; t < 4; t++) {
                af[t]  = *reinterpret_cast<const bf16x8*>(
                    &As[p * 4096 + (wm * 64 + t * 16 + l15) * 32 + quad * 8]);
                bfr[t] = *reinterpret_cast<const bf16x8*>(
                    &Bs[p * 4096 + (wn * 64 + t * 16 + l15) * 32 + quad * 8]);
            }
#pragma unroll
            for (int tm = 0; tm < 4; tm++)
#pragma unroll
                for (int tn = 0; tn < 4; tn++)
                    acc[tm][tn] = __builtin_amdgcn_mfma_f32_16x16x32_bf16(af[tm], bfr[tn], acc[tm][tn], 0, 0, 0);
        }
    }
    // ---- fused epilogue ----
    const int slot_base = n0 + wn * 64;       // wave-uniform
    const int G = slot_base / 384;
    const int slot = (slot_base % 384) / 64;
    const int bb = m0 >> 11;
    const int tb0 = (m0 & 2047) + wm * 64 + quad * 4;
    if (slot == 5) {
        u16* vbase = Vt + ((size_t)(bb * 8 + G) * 64) * 2048;
#pragma unroll
        for (int tm = 0; tm < 4; tm++) {
            const int trow = tb0 + tm * 16;
#pragma unroll
            for (int tn = 0; tn < 4; tn++) {
                const int d = tn * 16 + l15;
                uint2 pk;
                pk.x = pack_bf16(acc[tm][tn][0], acc[tm][tn][1]);
                pk.y = pack_bf16(acc[tm][tn][2], acc[tm][tn][3]);
                *reinterpret_cast<uint2*>(vbase + (size_t)d * 2048 + trow) = pk;
            }
        }
    } else {
        const float sc = (slot < 4) ? QSCALE : 1.0f;
        u16* obase = (slot < 4)
            ? Qo + ((size_t)(bb * 32 + G * 4 + slot) * 2048) * 64
            : Ko + ((size_t)(bb * 8 + G) * 2048) * 64;
#pragma unroll
        for (int tm = 0; tm < 4; tm++) {
#pragma unroll
            for (int i = 0; i < 4; i++) {
                const int t = tb0 + tm * 16 + i;
#pragma unroll
                for (int tn = 0; tn < 2; tn++) {
                    const int dh = tn * 16 + l15;
                    float c = cosb[t * 32 + dh], s = sinb[t * 32 + dh];
                    float x1 = acc[tm][tn][i], x2 = acc[tm][tn + 2][i];
                    obase[(size_t)t * 64 + dh]      = f2bf((x1 * c - x2 * s) * sc);
                    obase[(size_t)t * 64 + dh + 32] = f2bf((x2 * c + x1 * s) * sc);
                }
            }
        }
    }
}

// ---------- GEMM2: out[M,N] f32 = A[M,K] @ B[N,K]^T, BK=64 (two BK=32 panels) ----------
__global__ __launch_bounds__(256) void gemm_bt(const u16* __restrict__ A,
                                               const u16* __restrict__ Bw,
                                               float* __restrict__ Cf,
                                               int M, int N, int K) {
    __shared__ __align__(16) u16 As[2 * 128 * 32];
    __shared__ __align__(16) u16 Bs[2 * 128 * 32];
    const int tid = threadIdx.x;
    const int wave = tid >> 6, lane = tid & 63, quad = lane >> 4, l15 = lane & 15;
    const int wm = wave >> 1, wn = wave & 1;
    const int m0 = blockIdx.x * 128, n0 = blockIdx.y * 128;
    const int lrow = lane >> 2, lcol = (lane & 3) * 8;
    f32x4 acc[4][4];
#pragma unroll
    for (int a = 0; a < 4; a++)
#pragma unroll
        for (int b = 0; b < 4; b++) acc[a][b] = (f32x4){0.f, 0.f, 0.f, 0.f};
    for (int kk = 0; kk < K; kk += 64) {
        __syncthreads();
#pragma unroll
        for (int p = 0; p < 2; p++)
#pragma unroll
            for (int c = 0; c < 2; c++) {
                const int rA = wave * 32 + c * 16;
                gload16(A  + (size_t)(m0 + rA + lrow) * K + kk + p * 32 + lcol,
                        &As[p * 4096 + rA * 32]);
                gload16(Bw + (size_t)(n0 + rA + lrow) * K + kk + p * 32 + lcol,
                        &Bs[p * 4096 + rA * 32]);
            }
        __syncthreads();
#pragma unroll
        for (int p = 0; p < 2; p++) {
            bf16x8 af[4], bfr[4];
#pragma unroll
            for (int t = 0; t < 4; t++) {
                af[t]  = *reinterpret_cast<const bf16x8*>(
                    &As[p * 4096 + (wm * 64 + t * 16 + l15) * 32 + quad * 8]);
                bfr[t] = *reinterpret_cast<const bf16x8*>(
                    &Bs[p * 4096 + (wn * 64 + t * 16 + l15) * 32 + quad * 8]);
            }
#pragma unroll
            for (int tm = 0; tm < 4; tm++)
#pragma unroll
                for (int tn = 0; tn < 4; tn++)
                    acc[tm][tn] = __builtin_amdgcn_mfma_f32_16x16x32_bf16(af[tm], bfr[tn], acc[tm][tn], 0, 0, 0);
        }
    }
#pragma unroll
    for (int tm = 0; tm < 4; tm++) {
        const int r0 = m0 + wm * 64 + tm * 16 + quad * 4;
#pragma unroll
        for (int tn = 0; tn < 4; tn++) {
            const int c = n0 + wn * 64 + tn * 16 + l15;
#pragma unroll
            for (int i = 0; i < 4; i++) Cf[(size_t)(r0 + i) * N + c] = acc[tm][tn][i];
        }
    }
}

// ---------- flash attention v6: R3's proven skeleton (2-barrier staging, LDS-P
// round trip, 32x32x16) with fixed-max base-2 softmax (no running-max bookkeeping).
__global__ __launch_bounds__(256, 4) void attn(const u16* __restrict__ Q,
                                               const u16* __restrict__ Kg,
                                               const u16* __restrict__ Vt,
                                               u16* __restrict__ O) {
    constexpr int LDK = 72;
    constexpr int LDP = 88;
    __shared__ __align__(16) u16 Ks[64 * LDK];
    __shared__ __align__(16) u16 Vts[64 * LDK];
    __shared__ __align__(16) u16 Ps[4 * 32 * LDP];   // per-wave P; also Q staging scratch
    const int tid = threadIdx.x, w = tid >> 6, lane = tid & 63;
    const int half = lane >> 5, l31 = lane & 31;
    const int q0 = blockIdx.x * 128;
    const int h = blockIdx.y, b = blockIdx.z, g = h >> 2;
    const u16* qb = Q + (((size_t)(b * 32 + h)) * 2048 + q0) * 64;
    const u16* kb = Kg + ((size_t)(b * 8 + g)) * 2048 * 64;
    const u16* vb = Vt + ((size_t)(b * 8 + g)) * 64 * 2048;

    // stage Q (128x64) into Ps scratch, read per-wave B-fragments, then release
    {
        const int r = tid >> 3, c = tid & 7;
#pragma unroll
        for (int p = 0; p < 4; p++) {
            uint4 d = *reinterpret_cast<const uint4*>(qb + (size_t)(r + p * 32) * 64 + c * 8);
            *reinterpret_cast<uint4*>(&Ps[(r + p * 32) * LDK + c * 8]) = d;
        }
    }
    __syncthreads();
    bf16x8 qf[4];
#pragma unroll
    for (int ks = 0; ks < 4; ks++)
        qf[ks] = *reinterpret_cast<const bf16x8*>(&Ps[(w * 32 + l31) * LDK + ks * 16 + half * 8]);
    __syncthreads();

    f32x16 Oa[2];
#pragma unroll
    for (int t = 0; t < 2; t++)
#pragma unroll
        for (int i = 0; i < 16; i++) Oa[t][i] = 0.f;
    float lsum = 0.f;
    u16* Pw = Ps + w * 32 * LDP;

    for (int kk = 0; kk < 2048; kk += 64) {
        __syncthreads();
        {
            const int r = tid >> 3, c = tid & 7;
#pragma unroll
            for (int p = 0; p < 2; p++) {
                uint4 dk = *reinterpret_cast<const uint4*>(kb + (size_t)(kk + r + p * 32) * 64 + c * 8);
                *reinterpret_cast<uint4*>(&Ks[(r + p * 32) * LDK + c * 8]) = dk;
                uint4 dv = *reinterpret_cast<const uint4*>(vb + (size_t)(r + p * 32) * 2048 + kk + c * 8);
                *reinterpret_cast<uint4*>(&Vts[(r + p * 32) * LDK + c * 8]) = dv;
            }
        }
        __syncthreads();
        // S^T[key 64][q 32]: A = K-frag [key][d], B = Q-frag [q][d]
        f32x16 S[2];
#pragma unroll
        for (int kt = 0; kt < 2; kt++) {
#pragma unroll
            for (int i = 0; i < 16; i++) S[kt][i] = 0.f;
#pragma unroll
            for (int ks = 0; ks < 4; ks++) {
                bf16x8 kf = *reinterpret_cast<const bf16x8*>(
                    &Ks[(kt * 32 + l31) * LDK + ks * 16 + half * 8]);
                S[kt] = __builtin_amdgcn_mfma_f32_32x32x16_bf16(kf, qf[ks], S[kt], 0, 0, 0);
            }
        }
        // fixed-max base-2 softmax: p = exp2(s) directly (|s| bounded, no overflow)
        float ps = 0.f;
#pragma unroll
        for (int kt = 0; kt < 2; kt++)
#pragma unroll
            for (int gr = 0; gr < 4; gr++) {
                float p0 = __builtin_amdgcn_exp2f(S[kt][gr * 4 + 0]);
                float p1 = __builtin_amdgcn_exp2f(S[kt][gr * 4 + 1]);
                float p2 = __builtin_amdgcn_exp2f(S[kt][gr * 4 + 2]);
                float p3 = __builtin_amdgcn_exp2f(S[kt][gr * 4 + 3]);
                ps += (p0 + p1) + (p2 + p3);
                uint2 pk;
                pk.x = pack_bf16(p0, p1);
                pk.y = pack_bf16(p2, p3);
                *reinterpret_cast<uint2*>(&Pw[l31 * LDP + kt * 32 + gr * 8 + half * 4]) = pk;
            }
        lsum += ps;
        // O^T[d][q] += Vt-frag [d][key] x P-frag [q][key]  (per-wave Ps: no barrier)
#pragma unroll
        for (int ks2 = 0; ks2 < 4; ks2++) {
            bf16x8 pf = *reinterpret_cast<const bf16x8*>(&Pw[l31 * LDP + ks2 * 16 + half * 8]);
#pragma unroll
            for (int dt = 0; dt < 2; dt++) {
                bf16x8 vf = *reinterpret_cast<const bf16x8*>(
                    &Vts[(dt * 32 + l31) * LDK + ks2 * 16 + half * 8]);
                Oa[dt] = __builtin_amdgcn_mfma_f32_32x32x16_bf16(vf, pf, Oa[dt], 0, 0, 0);
            }
        }
    }
    float lt = lsum + __shfl_xor(lsum, 32);
    float linv = 1.f / lt;
    const int t = q0 + w * 32 + l31;
    u16* orow = O + ((size_t)(b * 2048 + t)) * 2048 + h * 64;
#pragma unroll
    for (int dt = 0; dt < 2; dt++)
#pragma unroll
        for (int gr = 0; gr < 4; gr++) {
            uint2 pk;
            pk.x = pack_bf16(Oa[dt][gr * 4 + 0] * linv, Oa[dt][gr * 4 + 1] * linv);
            pk.y = pack_bf16(Oa[dt][gr * 4 + 2] * linv, Oa[dt][gr * 4 + 3] * linv);
            *reinterpret_cast<uint2*>(orow + dt * 32 + 8 * gr + 4 * half) = pk;
        }
}

// ---------- launch ----------
extern "C" void kernel_launch(void* const* d_in, const int* in_sizes, int n_in,
                              void* d_out, int out_size, void* d_ws, size_t ws_size,
                              hipStream_t stream) {
    const float* x      = (const float*)d_in[0];
    const float* cosb   = (const float*)d_in[1];
    const float* sinb   = (const float*)d_in[2];
    const float* attn_w = (const float*)d_in[3];
    const float* proj_w = (const float*)d_in[4];
    float* out = (float*)d_out;

    u16* xb  = (u16*)d_ws;                       // 4096*2048
    u16* w1b = xb  + (size_t)4096 * 2048;        // 3072*2048
    u16* w2b = w1b + (size_t)3072 * 2048;        // 2048*2048
    u16* qo  = w2b + (size_t)2048 * 2048;        // 2*32*2048*64
    u16* ko  = qo  + (size_t)2 * 32 * 2048 * 64; // 2*8*2048*64
    u16* vt  = ko  + (size_t)2 * 8 * 2048 * 64;  // 2*8*64*2048 (transposed)
    u16* ao  = xb;   // attention output reuses x buffer (x consumed by gemm_qkv)

    cvt_kernel<<<8192, 256, 0, stream>>>(x, xb, 4096 * 2048 / 4);
    cvt_kernel<<<6144, 256, 0, stream>>>(attn_w, w1b, 3072 * 2048 / 4);
    cvt_kernel<<<4096, 256, 0, stream>>>(proj_w, w2b, 2048 * 2048 / 4);
    gemm_qkv<<<dim3(32, 24), 256, 0, stream>>>(xb, w1b, cosb, sinb, qo, ko, vt);
    attn<<<dim3(16, 32, 2), 256, 0, stream>>>(qo, ko, vt, ao);
    gemm_bt<<<dim3(32, 16), 256, 0, stream>>>(ao, w2b, out, 4096, 2048, 2048);
}